// Round 1
// baseline (20524.832 us; speedup 1.0000x reference)
//
#include <hip/hip_runtime.h>
#include <stdint.h>
#include <stddef.h>

typedef __bf16 bf16x8 __attribute__((ext_vector_type(8)));
typedef float f32x4 __attribute__((ext_vector_type(4)));

#define MFMA16(a, b, c) __builtin_amdgcn_mfma_f32_16x16x32_bf16((a), (b), (c), 0, 0, 0)

// problem dims
#define TSTEPS 1024
#define HID    256
#define NDIM   64
#define KTOT   352   // padded K for gates: 3(x) + 64(noise) + 256(h) = 323 -> 352
#define NKC    11    // KTOT/32
#define NGT    64    // 1024/16 gate row tiles
#define NHKC   8     // 256/32 head k chunks
#define NHT    16    // 256/16 head row tiles
#define MB     16    // batch rows per block
#define NBLK   32    // 32*16 = 512 batch

// workspace layout (bytes)
#define GOFF    ((size_t)0)
#define GBYTES  ((size_t)NGT * NKC * 1024)     // 720896
#define W1OFF   (GOFF + GBYTES)
#define W1BYTES ((size_t)NHT * NHKC * 1024)    // 131072
#define BOFF    (W1OFF + W1BYTES)              // gate bias (1024 f32, quad-reordered)
#define B1OFF   (BOFF + 4096)
#define W2OFF   (B1OFF + 1024)
#define B2OFF   (W2OFF + 1024)
#define WSNEED  (B2OFF + 16)

__device__ __forceinline__ uint16_t f2bf(float f) {
    union { float f; uint32_t u; } v; v.f = f;
    return (uint16_t)((v.u + 0x7FFFu + ((v.u >> 16) & 1u)) >> 16);  // RNE
}
__device__ __forceinline__ float fsig(float x) { return 1.0f / (1.0f + __expf(-x)); }
__device__ __forceinline__ float ftanh(float x) { return 2.0f / (1.0f + __expf(-2.0f * x)) - 1.0f; }

// ---- prep: gate weights [1024 x 352] bf16, rows interleaved rho = 4*unit + gate,
//      stored frag-major: frag F=(T*NKC+kc), lane l holds A[16T+(l&15)][32kc+8*(l>>4)+j]
__global__ void prep_gates(const float* __restrict__ W_ih, const float* __restrict__ W_hh,
                           char* __restrict__ ws) {
    int F = blockIdx.x;              // T*NKC + kc
    int T = F / NKC, kc = F - T * NKC;
    int l = threadIdx.x;             // 0..63
    int row  = 16 * T + (l & 15);    // rho
    int unit = row >> 2, gt = row & 3;
    int orig = gt * 256 + unit;      // torch gate order i,f,g,o blocks of 256
    uint32_t w[4];
#pragma unroll
    for (int p = 0; p < 4; ++p) {
        float v[2];
#pragma unroll
        for (int e = 0; e < 2; ++e) {
            int k = 32 * kc + 8 * (l >> 4) + 2 * p + e;
            float x = 0.f;
            if (k < 67)       { x = W_ih[orig * 67 + k]; if (k == 2) x *= 24.0f; }
            else if (k < 323) { x = W_hh[orig * 256 + (k - 67)]; }
            v[e] = x;
        }
        w[p] = (uint32_t)f2bf(v[0]) | ((uint32_t)f2bf(v[1]) << 16);
    }
    *(uint4*)(ws + GOFF + (size_t)F * 1024 + (size_t)l * 16) = make_uint4(w[0], w[1], w[2], w[3]);
}

// ---- prep: W1 [256 x 256] bf16, frag-major, natural row order
__global__ void prep_w1(const float* __restrict__ W1, char* __restrict__ ws) {
    int F = blockIdx.x;              // T*NHKC + kc
    int T = F / NHKC, kc = F - T * NHKC;
    int l = threadIdx.x;
    int row = 16 * T + (l & 15);
    uint32_t w[4];
#pragma unroll
    for (int p = 0; p < 4; ++p) {
        int k = 32 * kc + 8 * (l >> 4) + 2 * p;
        w[p] = (uint32_t)f2bf(W1[row * 256 + k]) | ((uint32_t)f2bf(W1[row * 256 + k + 1]) << 16);
    }
    *(uint4*)(ws + W1OFF + (size_t)F * 1024 + (size_t)l * 16) = make_uint4(w[0], w[1], w[2], w[3]);
}

// ---- prep: biases (gate bias quad-reordered), w2, b2
__global__ void prep_small(const float* __restrict__ b_ih, const float* __restrict__ b_hh,
                           const float* __restrict__ b1, const float* __restrict__ W2,
                           const float* __restrict__ b2, char* __restrict__ ws) {
    int t = threadIdx.x;
    float* sb  = (float*)(ws + BOFF);
    float* sb1 = (float*)(ws + B1OFF);
    float* sw2 = (float*)(ws + W2OFF);
    float* sb2 = (float*)(ws + B2OFF);
    if (t < 1024) {
        int unit = t >> 2, gt = t & 3;
        int orig = gt * 256 + unit;
        sb[t] = b_ih[orig] + b_hh[orig];
    }
    if (t < 256) { sb1[t] = b1[t]; sw2[t] = W2[t]; }
    if (t == 0)  sb2[0] = b2[0];
}

// ---- main recurrence: 32 blocks x 512 threads (8 waves), 16 batch rows/block
__global__ __launch_bounds__(512) void lstm_main(const float* __restrict__ noise,
                                                 const float* __restrict__ gap,
                                                 const char* __restrict__ ws,
                                                 float* __restrict__ out) {
    __shared__ uint16_t act[MB * 384];   // [batch][k], XOR-swizzled, bf16
    __shared__ uint16_t hbuf[MB * 256];  // aligned h copy for head B-operand
    __shared__ float dp_part[8][16];
    __shared__ float s_bias[1024];
    __shared__ float s_b1[256];
    __shared__ float s_w2[256];
    __shared__ float s_b2;

    const int tid  = threadIdx.x;
    const int wid  = tid >> 6;
    const int lane = tid & 63;
    const int q    = lane >> 4;
    const int col  = lane & 15;          // batch column
    const int b0   = blockIdx.x * MB;
    const int swz  = (col & 7) << 3;     // bank swizzle (in u16 elements)

    const uint4* gfr  = (const uint4*)(ws + GOFF);
    const uint4* w1fr = (const uint4*)(ws + W1OFF);

    for (int i = tid; i < MB * 384; i += 512) act[i] = 0;
    for (int i = tid; i < MB * 256; i += 512) hbuf[i] = 0;
    for (int i = tid; i < 1024; i += 512) s_bias[i] = ((const float*)(ws + BOFF))[i];
    if (tid < 256) { s_b1[tid] = ((const float*)(ws + B1OFF))[tid];
                     s_w2[tid] = ((const float*)(ws + W2OFF))[tid]; }
    if (tid == 0) s_b2 = ((const float*)(ws + B2OFF))[0];
    __syncthreads();

    float creg[8] = {0, 0, 0, 0, 0, 0, 0, 0};
    const f32x4 fz = {0.f, 0.f, 0.f, 0.f};

#pragma unroll 1
    for (int t = 0; t <= TSTEPS; ++t) {
        // ---- S1: head = tanh(W1 @ h + b1); dp partials. also stage noise(t).
        f32x4 h0 = fz, h1 = fz;
#pragma unroll
        for (int kc = 0; kc < NHKC; ++kc) {
            int k0 = 32 * kc + 8 * q;
            bf16x8 bv = *(const bf16x8*)&hbuf[col * 256 + (k0 ^ swz)];
            uint4 a0 = w1fr[(size_t)((2 * wid + 0) * NHKC + kc) * 64 + lane];
            uint4 a1 = w1fr[(size_t)((2 * wid + 1) * NHKC + kc) * 64 + lane];
            h0 = MFMA16(__builtin_bit_cast(bf16x8, a0), bv, h0);
            h1 = MFMA16(__builtin_bit_cast(bf16x8, a1), bv, h1);
        }
        float part = 0.f;
#pragma unroll
        for (int r = 0; r < 4; ++r) {
            int r0 = 16 * (2 * wid + 0) + 4 * q + r;
            int r1 = 16 * (2 * wid + 1) + 4 * q + r;
            part += ftanh(h0[r] + s_b1[r0]) * s_w2[r0];
            part += ftanh(h1[r] + s_b1[r1]) * s_w2[r1];
        }
        part += __shfl_xor(part, 16);
        part += __shfl_xor(part, 32);
        if (lane < 16) dp_part[wid][lane] = part;

        if (t < TSTEPS) {   // stage noise[b, t, :] -> act cols 3..66 (bf16)
            int br = tid >> 5;
            int j  = (tid & 31) * 2;
            const float* np = &noise[((size_t)(b0 + br) * TSTEPS + t) * NDIM + j];
            float n0 = np[0], n1 = np[1];
            int sw = (br & 7) << 3;
            act[br * 384 + ((3 + j)     ^ sw)] = f2bf(n0);
            act[br * 384 + ((3 + j + 1) ^ sw)] = f2bf(n1);
        }
        __syncthreads();

        // ---- S2: finalize dp, write outputs, stage x(t) = [gap0, gap1, tanh-val]
        if (tid < 16) {
            float inner = s_b2;
#pragma unroll
            for (int w = 0; w < 8; ++w) inner += dp_part[w][tid];
            float tdp = ftanh(inner);
            int gb = b0 + tid;
            float g0 = gap[((size_t)gb * (TSTEPS + 1) + t) * 2 + 0];
            float g1 = gap[((size_t)gb * (TSTEPS + 1) + t) * 2 + 1];
            float* o = out + ((size_t)gb * (TSTEPS + 1) + t) * 3;
            o[0] = g0; o[1] = g1; o[2] = 24.0f * tdp;
            int sw = (tid & 7) << 3;
            act[tid * 384 + (0 ^ sw)] = f2bf(g0);
            act[tid * 384 + (1 ^ sw)] = f2bf(g1);
            act[tid * 384 + (2 ^ sw)] = f2bf(tdp);   // W_ih col2 pre-scaled by 24
        }
        __syncthreads();
        if (t == TSTEPS) break;

        // ---- S3: gates[1024 x 16] = Wcat @ act^T  (A streamed from L2, frag-major)
        f32x4 gacc[8];
#pragma unroll
        for (int rt = 0; rt < 8; ++rt) gacc[rt] = fz;
#pragma unroll
        for (int kc = 0; kc < NKC; ++kc) {
            int k0 = 32 * kc + 8 * q;
            bf16x8 bv = *(const bf16x8*)&act[col * 384 + (k0 ^ swz)];
#pragma unroll
            for (int rt = 0; rt < 8; ++rt) {
                uint4 av = gfr[(size_t)((8 * wid + rt) * NKC + kc) * 64 + lane];
                gacc[rt] = MFMA16(__builtin_bit_cast(bf16x8, av), bv, gacc[rt]);
            }
        }
        __syncthreads();

        // ---- S4: lane-local LSTM elementwise (lane's 4 acc regs = i,f,g,o of one unit)
#pragma unroll
        for (int rt = 0; rt < 8; ++rt) {
            int T  = 8 * wid + rt;
            int rb = 16 * T + 4 * q;
            float ii = gacc[rt][0] + s_bias[rb + 0];
            float ff = gacc[rt][1] + s_bias[rb + 1];
            float gg = gacc[rt][2] + s_bias[rb + 2];
            float oo = gacc[rt][3] + s_bias[rb + 3];
            float cn = fsig(ff) * creg[rt] + fsig(ii) * ftanh(gg);
            creg[rt] = cn;
            float hv = fsig(oo) * ftanh(cn);
            uint16_t hb = f2bf(hv);
            int unit = 4 * T + q;
            act[col * 384 + ((67 + unit) ^ swz)] = hb;
            hbuf[col * 256 + (unit ^ swz)]       = hb;
        }
        __syncthreads();
    }
}

extern "C" void kernel_launch(void* const* d_in, const int* in_sizes, int n_in,
                              void* d_out, int out_size, void* d_ws, size_t ws_size,
                              hipStream_t stream) {
    (void)in_sizes; (void)n_in; (void)out_size;
    if (ws_size < WSNEED) return;  // fail loudly (output stays poisoned)

    const float* noise = (const float*)d_in[0];
    const float* gap   = (const float*)d_in[1];
    const float* W_ih  = (const float*)d_in[2];
    const float* W_hh  = (const float*)d_in[3];
    const float* b_ih  = (const float*)d_in[4];
    const float* b_hh  = (const float*)d_in[5];
    const float* W1    = (const float*)d_in[6];
    const float* b1    = (const float*)d_in[7];
    const float* W2    = (const float*)d_in[8];
    const float* b2    = (const float*)d_in[9];
    char*  ws  = (char*)d_ws;
    float* out = (float*)d_out;

    hipLaunchKernelGGL(prep_gates, dim3(NGT * NKC), dim3(64), 0, stream, W_ih, W_hh, ws);
    hipLaunchKernelGGL(prep_w1,    dim3(NHT * NHKC), dim3(64), 0, stream, W1, ws);
    hipLaunchKernelGGL(prep_small, dim3(1), dim3(1024), 0, stream, b_ih, b_hh, b1, W2, b2, ws);
    hipLaunchKernelGGL(lstm_main,  dim3(NBLK), dim3(512), 0, stream, noise, gap, ws, out);
}

// Round 2
// 18473.116 us; speedup vs baseline: 1.1111x; 1.1111x over previous
//
#include <hip/hip_runtime.h>
#include <stdint.h>
#include <stddef.h>

typedef __bf16 bf16x8 __attribute__((ext_vector_type(8)));
typedef float f32x4 __attribute__((ext_vector_type(4)));

#define MFMA16(a, b, c) __builtin_amdgcn_mfma_f32_16x16x32_bf16((a), (b), (c), 0, 0, 0)

// problem dims
#define TSTEPS 1024
#define NDIM   64
#define NKC    11     // K = 352 padded: 0,1 gap | 2 dp | 3 pad | 4..67 noise | 68..323 h | pad
#define NGT    64     // 1024/16 gate row tiles
#define MB     16     // batch rows per group
#define GROUPS 32
#define SLICES 8      // blocks per group; each owns 32 hidden units

// workspace layout (bytes)
#define GOFF    ((size_t)0)
#define GBYTES  ((size_t)NGT * NKC * 1024)       // 720896
#define W1OFF   (GOFF + GBYTES)
#define W1BYTES ((size_t)16 * 8 * 1024)          // 131072
#define BOFF    (W1OFF + W1BYTES)                // 1024 f32 reordered gate bias
#define FOFF    (BOFF + 4096)                    // 256 u32 flags
#define XOFF    (FOFF + 1024)                    // payload: 32 groups * 8 slices * 2 parity * 1KB
#define XBYTES  ((size_t)GROUPS * SLICES * 2 * 1024)
#define WSNEED  (XOFF + XBYTES)

__device__ __forceinline__ uint16_t f2bf(float f) {
    union { float f; uint32_t u; } v; v.f = f;
    return (uint16_t)((v.u + 0x7FFFu + ((v.u >> 16) & 1u)) >> 16);  // RNE
}
__device__ __forceinline__ float fsig(float x) { return 1.0f / (1.0f + __expf(-x)); }
__device__ __forceinline__ float ftanh(float x) { return 2.0f / (1.0f + __expf(-2.0f * x)) - 1.0f; }

// ---- prep: gate weights [1024 x 352] bf16, rows interleaved rho = 4*unit + gate,
//      frag-major: frag F=(T*NKC+kc), lane l holds A[16T+(l&15)][32kc+8*(l>>4)+j]
//      k map: 0,1 -> gap cols; 2 -> dp col (prescaled x24); 3 -> 0; 4..67 -> noise; 68..323 -> h
__global__ void prep_gates(const float* __restrict__ W_ih, const float* __restrict__ W_hh,
                           char* __restrict__ ws) {
    int F = blockIdx.x;
    int T = F / NKC, kc = F - T * NKC;
    int l = threadIdx.x;
    int row  = 16 * T + (l & 15);
    int unit = row >> 2, gt = row & 3;
    int orig = gt * 256 + unit;              // torch gate order i,f,g,o blocks of 256
    uint32_t w[4];
#pragma unroll
    for (int p = 0; p < 4; ++p) {
        float v[2];
#pragma unroll
        for (int e = 0; e < 2; ++e) {
            int k = 32 * kc + 8 * (l >> 4) + 2 * p + e;
            float x = 0.f;
            if (k < 2)        { x = W_ih[orig * 67 + k]; }
            else if (k == 2)  { x = W_ih[orig * 67 + 2] * 24.0f; }
            else if (k == 3)  { x = 0.f; }
            else if (k < 68)  { x = W_ih[orig * 67 + (k - 1)]; }
            else if (k < 324) { x = W_hh[orig * 256 + (k - 68)]; }
            v[e] = x;
        }
        w[p] = (uint32_t)f2bf(v[0]) | ((uint32_t)f2bf(v[1]) << 16);
    }
    *(uint4*)(ws + GOFF + (size_t)F * 1024 + (size_t)l * 16) = make_uint4(w[0], w[1], w[2], w[3]);
}

// ---- prep: W1 [256 x 256] bf16, frag-major
__global__ void prep_w1(const float* __restrict__ W1, char* __restrict__ ws) {
    int F = blockIdx.x;
    int T = F / 8, kc = F - T * 8;
    int l = threadIdx.x;
    int row = 16 * T + (l & 15);
    uint32_t w[4];
#pragma unroll
    for (int p = 0; p < 4; ++p) {
        int k = 32 * kc + 8 * (l >> 4) + 2 * p;
        w[p] = (uint32_t)f2bf(W1[row * 256 + k]) | ((uint32_t)f2bf(W1[row * 256 + k + 1]) << 16);
    }
    *(uint4*)(ws + W1OFF + (size_t)F * 1024 + (size_t)l * 16) = make_uint4(w[0], w[1], w[2], w[3]);
}

// ---- prep: reordered gate bias + zero the sync flags (fresh every call / graph replay)
__global__ void prep_small(const float* __restrict__ b_ih, const float* __restrict__ b_hh,
                           char* __restrict__ ws) {
    int t = threadIdx.x;
    float* sb = (float*)(ws + BOFF);
    unsigned int* fl = (unsigned int*)(ws + FOFF);
    if (t < 1024) {
        int unit = t >> 2, gt = t & 3;
        int orig = gt * 256 + unit;
        sb[t] = b_ih[orig] + b_hh[orig];
    }
    if (t < 256) fl[t] = 0u;
}

// ---- main: 256 blocks (32 groups x 8 slices), 512 threads, weights in VGPRs
__global__ __launch_bounds__(512, 2) void lstm_main(
        const float* __restrict__ noise, const float* __restrict__ gap,
        const float* __restrict__ b1p, const float* __restrict__ W2p,
        const float* __restrict__ b2p, char* __restrict__ ws,
        float* __restrict__ out) {
    __shared__ uint16_t act[MB * 384];   // [batch][k], XOR-swizzled, bf16
    __shared__ uint16_t hbuf[MB * 256];  // h at base 0 for head B-operand
    __shared__ float dp_part[16][8];

    const int tid  = threadIdx.x;
    const int w    = tid >> 6;
    const int lane = tid & 63;
    const int q    = lane >> 4;
    const int col  = lane & 15;
    const int g    = blockIdx.x >> 3;
    const int s    = blockIdx.x & 7;
    const int b0   = g * MB;
    const int swz  = (col & 7) << 3;

    const uint4* gfr  = (const uint4*)(ws + GOFF);
    const uint4* w1fr = (const uint4*)(ws + W1OFF);
    const float* bias = (const float*)(ws + BOFF);
    unsigned int* flags = (unsigned int*)(ws + FOFF);
    unsigned long long* pay = (unsigned long long*)(ws + XOFF);

    for (int i = tid; i < MB * 384; i += 512) act[i] = 0;
    for (int i = tid; i < MB * 256; i += 512) hbuf[i] = 0;

    // ---- weights -> VGPRs
    const int T = 8 * s + w;             // this wave's gate row-tile (global)
    uint4 gw[11];
#pragma unroll
    for (int kc = 0; kc < 11; ++kc) gw[kc] = gfr[(size_t)(T * 11 + kc) * 64 + lane];
    uint4 w1w[16];                        // full W1: wave w holds head row-tiles 2w, 2w+1
#pragma unroll
    for (int i = 0; i < 2; ++i)
#pragma unroll
        for (int kc = 0; kc < 8; ++kc)
            w1w[i * 8 + kc] = w1fr[(size_t)((2 * w + i) * 8 + kc) * 64 + lane];

    const int rb = 16 * T + 4 * q;
    const float bI = bias[rb], bF = bias[rb + 1], bG = bias[rb + 2], bO = bias[rb + 3];
    float b1r[8], w2r[8];
#pragma unroll
    for (int a = 0; a < 2; ++a)
#pragma unroll
        for (int r = 0; r < 4; ++r) {
            int row = 32 * w + 16 * a + 4 * q + r;
            b1r[4 * a + r] = b1p[row];
            w2r[4 * a + r] = W2p[row];
        }
    const float b2v = b2p[0];

    // ---- prefetch t=0
    const int nbr = tid >> 5, nj = (tid & 31) * 2;
    const float* nptr = noise + (size_t)(b0 + nbr) * TSTEPS * NDIM + nj;
    float2 npf = *(const float2*)nptr;
    const bool xlead = (w == 0 && lane < 16);
    float2 gpf = make_float2(0.f, 0.f);
    if (xlead) gpf = *(const float2*)(gap + (size_t)(b0 + col) * (TSTEPS + 1) * 2);

    float creg = 0.f;
    const f32x4 fz = {0.f, 0.f, 0.f, 0.f};
    const unsigned myflag = (unsigned)(g * 8 + s);

    __syncthreads();

#pragma unroll 1
    for (int t = 0; t <= TSTEPS; ++t) {
        // ---- Phase A: h-slice exchange (t>0) + noise staging + prefetch
        if (t > 0) {
            if (w == 0) {
                int k2 = lane >> 4;  // 0..3
                uint64_t a = *(const uint64_t*)&hbuf[col * 256 + ((32 * s + 4 * k2) ^ swz)];
                uint64_t b = *(const uint64_t*)&hbuf[col * 256 + ((32 * s + 4 * (k2 + 4)) ^ swz)];
                unsigned long long* dst = pay + ((size_t)(g * 8 + s) * 2 + (t & 1)) * 128;
                __hip_atomic_store(dst + col * 8 + k2,     a, __ATOMIC_RELAXED, __HIP_MEMORY_SCOPE_AGENT);
                __hip_atomic_store(dst + col * 8 + k2 + 4, b, __ATOMIC_RELAXED, __HIP_MEMORY_SCOPE_AGENT);
                if (lane == 0)
                    __hip_atomic_store(&flags[myflag], (unsigned)t, __ATOMIC_RELEASE, __HIP_MEMORY_SCOPE_AGENT);
            } else {
                int p = (s + w) & 7;
                while (__hip_atomic_load(&flags[g * 8 + p], __ATOMIC_RELAXED,
                                         __HIP_MEMORY_SCOPE_AGENT) < (unsigned)t) {}
                __builtin_amdgcn_fence(__ATOMIC_ACQUIRE, "agent");
                const unsigned long long* src = pay + ((size_t)(g * 8 + p) * 2 + (t & 1)) * 128;
                int k2 = lane >> 4;
                uint64_t a = __hip_atomic_load(src + col * 8 + k2,     __ATOMIC_RELAXED, __HIP_MEMORY_SCOPE_AGENT);
                uint64_t b = __hip_atomic_load(src + col * 8 + k2 + 4, __ATOMIC_RELAXED, __HIP_MEMORY_SCOPE_AGENT);
                *(uint64_t*)&act[col * 384 + ((68 + 32 * p + 4 * k2) ^ swz)]      = a;
                *(uint64_t*)&hbuf[col * 256 + ((32 * p + 4 * k2) ^ swz)]          = a;
                *(uint64_t*)&act[col * 384 + ((68 + 32 * p + 4 * (k2 + 4)) ^ swz)] = b;
                *(uint64_t*)&hbuf[col * 256 + ((32 * p + 4 * (k2 + 4)) ^ swz)]     = b;
            }
        }
        if (t < TSTEPS) {   // stage noise(t) from prefetch regs
            uint32_t nv = (uint32_t)f2bf(npf.x) | ((uint32_t)f2bf(npf.y) << 16);
            int sw = (nbr & 7) << 3;
            *(uint32_t*)&act[nbr * 384 + ((4 + nj) ^ sw)] = nv;
        }
        if (t + 1 < TSTEPS) npf = *(const float2*)(nptr + (size_t)(t + 1) * NDIM);
        __syncthreads();

        // ---- Phase B: full head (redundant per block), dp, x staging, out
        f32x4 h0 = fz, h1 = fz;
#pragma unroll
        for (int kc = 0; kc < 8; ++kc) {
            bf16x8 bv = *(const bf16x8*)&hbuf[col * 256 + ((32 * kc + 8 * q) ^ swz)];
            h0 = MFMA16(__builtin_bit_cast(bf16x8, w1w[kc]),     bv, h0);
            h1 = MFMA16(__builtin_bit_cast(bf16x8, w1w[8 + kc]), bv, h1);
        }
        float part = 0.f;
#pragma unroll
        for (int r = 0; r < 4; ++r) {
            part += ftanh(h0[r] + b1r[r])     * w2r[r];
            part += ftanh(h1[r] + b1r[4 + r]) * w2r[4 + r];
        }
        part += __shfl_xor(part, 16);
        part += __shfl_xor(part, 32);
        if (q == 0) dp_part[col][w] = part;
        __syncthreads();

        if (xlead) {
            const float* dpp = &dp_part[col][0];
            float inner = b2v + ((dpp[0] + dpp[1]) + (dpp[2] + dpp[3]))
                              + ((dpp[4] + dpp[5]) + (dpp[6] + dpp[7]));
            float tdp = ftanh(inner);
            act[col * 384 + (0 ^ swz)] = f2bf(gpf.x);
            act[col * 384 + (1 ^ swz)] = f2bf(gpf.y);
            act[col * 384 + (2 ^ swz)] = f2bf(tdp);
            if (s == 0) {
                float* o = out + ((size_t)(b0 + col) * (TSTEPS + 1) + t) * 3;
                o[0] = gpf.x; o[1] = gpf.y; o[2] = 24.0f * tdp;
            }
        }
        if (xlead && t < TSTEPS)
            gpf = *(const float2*)(gap + ((size_t)(b0 + col) * (TSTEPS + 1) + (t + 1)) * 2);
        __syncthreads();
        if (t == TSTEPS) break;

        // ---- Phase C: gate slice (1 row-tile/wave), lane-local LSTM update
        f32x4 ga = fz;
#pragma unroll
        for (int kc = 0; kc < 11; ++kc) {
            bf16x8 bv = *(const bf16x8*)&act[col * 384 + ((32 * kc + 8 * q) ^ swz)];
            ga = MFMA16(__builtin_bit_cast(bf16x8, gw[kc]), bv, ga);
        }
        float ii = ga[0] + bI, ff = ga[1] + bF, gg = ga[2] + bG, oo = ga[3] + bO;
        float cn = fsig(ff) * creg + fsig(ii) * ftanh(gg);
        creg = cn;
        float hv = fsig(oo) * ftanh(cn);
        uint16_t hb = f2bf(hv);
        const int u = 32 * s + 4 * w + q;
        act[col * 384 + ((68 + u) ^ swz)] = hb;
        hbuf[col * 256 + (u ^ swz)]       = hb;
        __syncthreads();
    }
}

extern "C" void kernel_launch(void* const* d_in, const int* in_sizes, int n_in,
                              void* d_out, int out_size, void* d_ws, size_t ws_size,
                              hipStream_t stream) {
    (void)in_sizes; (void)n_in; (void)out_size;
    if (ws_size < WSNEED) return;  // fail loudly (output stays poisoned)

    const float* noise = (const float*)d_in[0];
    const float* gap   = (const float*)d_in[1];
    const float* W_ih  = (const float*)d_in[2];
    const float* W_hh  = (const float*)d_in[3];
    const float* b_ih  = (const float*)d_in[4];
    const float* b_hh  = (const float*)d_in[5];
    const float* W1    = (const float*)d_in[6];
    const float* b1    = (const float*)d_in[7];
    const float* W2    = (const float*)d_in[8];
    const float* b2    = (const float*)d_in[9];
    char*  ws  = (char*)d_ws;
    float* out = (float*)d_out;

    hipLaunchKernelGGL(prep_gates, dim3(NGT * NKC), dim3(64), 0, stream, W_ih, W_hh, ws);
    hipLaunchKernelGGL(prep_w1,    dim3(16 * 8),    dim3(64), 0, stream, W1, ws);
    hipLaunchKernelGGL(prep_small, dim3(1), dim3(1024), 0, stream, b_ih, b_hh, ws);
    hipLaunchKernelGGL(lstm_main,  dim3(GROUPS * SLICES), dim3(512), 0, stream,
                       noise, gap, b1, W2, b2, ws, out);
}

// Round 3
// 5206.147 us; speedup vs baseline: 3.9424x; 3.5483x over previous
//
#include <hip/hip_runtime.h>
#include <stdint.h>
#include <stddef.h>

typedef __bf16 bf16x8 __attribute__((ext_vector_type(8)));
typedef float f32x4 __attribute__((ext_vector_type(4)));

#define MFMA16(a, b, c) __builtin_amdgcn_mfma_f32_16x16x32_bf16((a), (b), (c), 0, 0, 0)

// problem dims
#define TSTEPS 1024
#define NDIM   64
#define NKC    11     // K = 352: 0,1 gap | 2 dp | 3 pad | 4..67 noise | 68..71 pad | 72..327 h
#define NGT    64     // 1024/16 gate row tiles
#define MB     16     // batch rows per group
#define GROUPS 32
#define SLICES 8      // blocks per group; each owns 32 hidden units

// workspace layout (bytes)
#define GOFF    ((size_t)0)
#define GBYTES  ((size_t)NGT * NKC * 1024)       // 720896
#define W1OFF   (GOFF + GBYTES)
#define W1BYTES ((size_t)16 * 8 * 1024)          // 131072
#define BOFF    (W1OFF + W1BYTES)                // 1024 f32 reordered gate bias
#define FOFF    (BOFF + 4096)                    // 256 flags, one per 64B line
#define FBYTES  ((size_t)256 * 64)
#define XOFF    (FOFF + FBYTES)                  // payload: 32g * 8s * 2 parity * 1KB
#define XBYTES  ((size_t)GROUPS * SLICES * 2 * 1024)
#define WSNEED  (XOFF + XBYTES)

__device__ __forceinline__ uint16_t f2bf(float f) {
    union { float f; uint32_t u; } v; v.f = f;
    return (uint16_t)((v.u + 0x7FFFu + ((v.u >> 16) & 1u)) >> 16);  // RNE
}
__device__ __forceinline__ float fsig(float x) { return 1.0f / (1.0f + __expf(-x)); }
__device__ __forceinline__ float ftanh(float x) { return 2.0f / (1.0f + __expf(-2.0f * x)) - 1.0f; }

// ---- prep: gate weights [1024 x 352] bf16, rows interleaved rho = 4*unit + gate,
//      frag-major: frag F=(T*NKC+kc), lane l holds A[16T+(l&15)][32kc+8*(l>>4)+j]
__global__ void prep_gates(const float* __restrict__ W_ih, const float* __restrict__ W_hh,
                           char* __restrict__ ws) {
    int F = blockIdx.x;
    int T = F / NKC, kc = F - T * NKC;
    int l = threadIdx.x;
    int row  = 16 * T + (l & 15);
    int unit = row >> 2, gt = row & 3;
    int orig = gt * 256 + unit;              // torch gate order i,f,g,o blocks of 256
    uint32_t w[4];
#pragma unroll
    for (int p = 0; p < 4; ++p) {
        float v[2];
#pragma unroll
        for (int e = 0; e < 2; ++e) {
            int k = 32 * kc + 8 * (l >> 4) + 2 * p + e;
            float x = 0.f;
            if (k < 2)        { x = W_ih[orig * 67 + k]; }
            else if (k == 2)  { x = W_ih[orig * 67 + 2] * 24.0f; }
            else if (k < 4)   { x = 0.f; }
            else if (k < 68)  { x = W_ih[orig * 67 + (k - 1)]; }
            else if (k < 72)  { x = 0.f; }
            else if (k < 328) { x = W_hh[orig * 256 + (k - 72)]; }
            v[e] = x;
        }
        w[p] = (uint32_t)f2bf(v[0]) | ((uint32_t)f2bf(v[1]) << 16);
    }
    *(uint4*)(ws + GOFF + (size_t)F * 1024 + (size_t)l * 16) = make_uint4(w[0], w[1], w[2], w[3]);
}

// ---- prep: W1 [256 x 256] bf16, frag-major
__global__ void prep_w1(const float* __restrict__ W1, char* __restrict__ ws) {
    int F = blockIdx.x;
    int T = F / 8, kc = F - T * 8;
    int l = threadIdx.x;
    int row = 16 * T + (l & 15);
    uint32_t w[4];
#pragma unroll
    for (int p = 0; p < 4; ++p) {
        int k = 32 * kc + 8 * (l >> 4) + 2 * p;
        w[p] = (uint32_t)f2bf(W1[row * 256 + k]) | ((uint32_t)f2bf(W1[row * 256 + k + 1]) << 16);
    }
    *(uint4*)(ws + W1OFF + (size_t)F * 1024 + (size_t)l * 16) = make_uint4(w[0], w[1], w[2], w[3]);
}

// ---- prep: reordered gate bias + zero sync flags (fresh every call / graph replay)
__global__ void prep_small(const float* __restrict__ b_ih, const float* __restrict__ b_hh,
                           char* __restrict__ ws) {
    int t = threadIdx.x;
    float* sb = (float*)(ws + BOFF);
    unsigned int* fl = (unsigned int*)(ws + FOFF);
    if (t < 1024) {
        int unit = t >> 2, gt = t & 3;
        int orig = gt * 256 + unit;
        sb[t] = b_ih[orig] + b_hh[orig];
    }
    if (t < 256) fl[t * 16] = 0u;
}

// ---- main: 256 blocks (32 groups x 8 slices), 512 threads, weights in VGPRs
__global__ __launch_bounds__(512, 2) void lstm_main(
        const float* __restrict__ noise, const float* __restrict__ gap,
        const float* __restrict__ b1p, const float* __restrict__ W2p,
        const float* __restrict__ b2p, char* __restrict__ ws,
        float* __restrict__ out) {
    __shared__ uint16_t act[MB * 384];   // [batch][k], XOR-swizzled, bf16
    __shared__ uint16_t hbuf[MB * 256];  // h at base 0 for head B-operand
    __shared__ float dp_part[16][8];

    const int tid  = threadIdx.x;
    const int w    = tid >> 6;
    const int lane = tid & 63;
    const int q    = lane >> 4;
    const int col  = lane & 15;
    const int g    = blockIdx.x >> 3;
    const int s    = blockIdx.x & 7;
    const int b0   = g * MB;
    const int swz  = (col & 7) << 3;

    const uint4* gfr  = (const uint4*)(ws + GOFF);
    const uint4* w1fr = (const uint4*)(ws + W1OFF);
    const float* bias = (const float*)(ws + BOFF);
    unsigned int* flags = (unsigned int*)(ws + FOFF);
    unsigned long long* pay = (unsigned long long*)(ws + XOFF);

    for (int i = tid; i < MB * 384; i += 512) act[i] = 0;
    for (int i = tid; i < MB * 256; i += 512) hbuf[i] = 0;

    // ---- weights -> VGPRs
    const int T = 8 * s + w;             // this wave's gate row-tile (global)
    uint4 gw[11];
#pragma unroll
    for (int kc = 0; kc < 11; ++kc) gw[kc] = gfr[(size_t)(T * 11 + kc) * 64 + lane];
    uint4 w1w[16];                        // full W1: wave w holds head row-tiles 2w, 2w+1
#pragma unroll
    for (int i = 0; i < 2; ++i)
#pragma unroll
        for (int kc = 0; kc < 8; ++kc)
            w1w[i * 8 + kc] = w1fr[(size_t)((2 * w + i) * 8 + kc) * 64 + lane];

    const int rb = 16 * T + 4 * q;
    const float bI = bias[rb], bF = bias[rb + 1], bG = bias[rb + 2], bO = bias[rb + 3];
    float b1r[8], w2r[8];
#pragma unroll
    for (int a = 0; a < 2; ++a)
#pragma unroll
        for (int r = 0; r < 4; ++r) {
            int row = 32 * w + 16 * a + 4 * q + r;
            b1r[4 * a + r] = b1p[row];
            w2r[4 * a + r] = W2p[row];
        }
    const float b2v = b2p[0];

    // ---- prefetch t=0
    const int nbr = tid >> 5, nj = (tid & 31) * 2;
    const float* nptr = noise + (size_t)(b0 + nbr) * TSTEPS * NDIM + nj;
    float2 npf = *(const float2*)nptr;
    const bool xlead = (w == 7 && lane < 16);   // epilogue wave (wave 0 is the sync wave)
    float2 gpf = make_float2(0.f, 0.f);
    if (xlead) gpf = *(const float2*)(gap + (size_t)(b0 + col) * (TSTEPS + 1) * 2);

    float creg = 0.f;
    const f32x4 fz = {0.f, 0.f, 0.f, 0.f};
    const int myidx = g * 8 + s;

    __syncthreads();

#pragma unroll 1
    for (int t = 0; t <= TSTEPS; ++t) {
        // ---- Phase A: noise staging (all waves) + h exchange (wave 0 only)
        if (t < TSTEPS) {   // stage noise(t) from prefetch regs
            uint32_t nv = (uint32_t)f2bf(npf.x) | ((uint32_t)f2bf(npf.y) << 16);
            int sw = (nbr & 7) << 3;
            *(uint32_t*)&act[nbr * 384 + ((4 + nj) ^ sw)] = nv;
        }
        if (t > 0 && w == 0) {
            const int pcol = lane >> 2, chunk = lane & 3;
            const int sw = (pcol & 7) << 3;
            // publish own 32-unit slice (16 cols x 32 units = 1KB)
            uint4 own = *(const uint4*)&hbuf[pcol * 256 + ((32 * s + 8 * chunk) ^ sw)];
            unsigned long long* dst = pay + ((size_t)myidx * 2 + (t & 1)) * 128 + 2 * lane;
            __hip_atomic_store(dst,     ((const unsigned long long*)&own)[0],
                               __ATOMIC_RELAXED, __HIP_MEMORY_SCOPE_AGENT);
            __hip_atomic_store(dst + 1, ((const unsigned long long*)&own)[1],
                               __ATOMIC_RELAXED, __HIP_MEMORY_SCOPE_AGENT);
            asm volatile("s_waitcnt vmcnt(0)" ::: "memory");   // payload at coherent point
            if (lane == 0)
                __hip_atomic_store(&flags[myidx * 16], (unsigned)t,
                                   __ATOMIC_RELAXED, __HIP_MEMORY_SCOPE_AGENT);
            // poll all 7 peer flags with 7 lanes; no acquire fence (payload reads are
            // coherent-point reads; L3 state is monotone)
            if (lane < 7) {
                const unsigned int* fp = &flags[(g * 8 + ((s + 1 + lane) & 7)) * 16];
                while (__hip_atomic_load(fp, __ATOMIC_RELAXED,
                                         __HIP_MEMORY_SCOPE_AGENT) < (unsigned)t) {}
            }
            asm volatile("" ::: "memory");   // compiler fence: no hoisting of payload reads
            // gather 7 peer slices -> act + hbuf
#pragma unroll
            for (int pi = 0; pi < 7; ++pi) {
                int p = (s + 1 + pi) & 7;
                const unsigned long long* src =
                    pay + ((size_t)(g * 8 + p) * 2 + (t & 1)) * 128 + 2 * lane;
                unsigned long long a = __hip_atomic_load(src,     __ATOMIC_RELAXED,
                                                         __HIP_MEMORY_SCOPE_AGENT);
                unsigned long long b = __hip_atomic_load(src + 1, __ATOMIC_RELAXED,
                                                         __HIP_MEMORY_SCOPE_AGENT);
                uint4 v;
                v.x = (uint32_t)a; v.y = (uint32_t)(a >> 32);
                v.z = (uint32_t)b; v.w = (uint32_t)(b >> 32);
                *(uint4*)&act[pcol * 384 + ((72 + 32 * p + 8 * chunk) ^ sw)] = v;
                *(uint4*)&hbuf[pcol * 256 + ((32 * p + 8 * chunk) ^ sw)]     = v;
            }
        }
        if (t + 1 < TSTEPS) npf = *(const float2*)(nptr + (size_t)(t + 1) * NDIM);
        __syncthreads();

        // ---- Phase B: full head (redundant per block), dp partials
        f32x4 h0 = fz, h1 = fz;
#pragma unroll
        for (int kc = 0; kc < 8; ++kc) {
            bf16x8 bv = *(const bf16x8*)&hbuf[col * 256 + ((32 * kc + 8 * q) ^ swz)];
            h0 = MFMA16(__builtin_bit_cast(bf16x8, w1w[kc]),     bv, h0);
            h1 = MFMA16(__builtin_bit_cast(bf16x8, w1w[8 + kc]), bv, h1);
        }
        float part = 0.f;
#pragma unroll
        for (int r = 0; r < 4; ++r) {
            part += ftanh(h0[r] + b1r[r])     * w2r[r];
            part += ftanh(h1[r] + b1r[4 + r]) * w2r[4 + r];
        }
        part += __shfl_xor(part, 16);
        part += __shfl_xor(part, 32);
        if (q == 0) dp_part[col][w] = part;
        __syncthreads();

        // ---- epilogue wave: finalize dp, write out, stage x(t)
        if (xlead) {
            const float* dpp = &dp_part[col][0];
            float inner = b2v + ((dpp[0] + dpp[1]) + (dpp[2] + dpp[3]))
                              + ((dpp[4] + dpp[5]) + (dpp[6] + dpp[7]));
            float tdp = ftanh(inner);
            act[col * 384 + (0 ^ swz)] = f2bf(gpf.x);
            act[col * 384 + (1 ^ swz)] = f2bf(gpf.y);
            act[col * 384 + (2 ^ swz)] = f2bf(tdp);
            if (s == 0) {
                float* o = out + ((size_t)(b0 + col) * (TSTEPS + 1) + t) * 3;
                o[0] = gpf.x; o[1] = gpf.y; o[2] = 24.0f * tdp;
            }
        }
        if (xlead && t < TSTEPS)
            gpf = *(const float2*)(gap + ((size_t)(b0 + col) * (TSTEPS + 1) + (t + 1)) * 2);
        __syncthreads();
        if (t == TSTEPS) break;

        // ---- Phase C: gate slice (1 row-tile/wave), lane-local LSTM update
        f32x4 ga = fz;
#pragma unroll
        for (int kc = 0; kc < 11; ++kc) {
            bf16x8 bv = *(const bf16x8*)&act[col * 384 + ((32 * kc + 8 * q) ^ swz)];
            ga = MFMA16(__builtin_bit_cast(bf16x8, gw[kc]), bv, ga);
        }
        float ii = ga[0] + bI, ff = ga[1] + bF, gg = ga[2] + bG, oo = ga[3] + bO;
        float cn = fsig(ff) * creg + fsig(ii) * ftanh(gg);
        creg = cn;
        float hv = fsig(oo) * ftanh(cn);
        uint16_t hb = f2bf(hv);
        const int u = 32 * s + 4 * w + q;
        act[col * 384 + ((72 + u) ^ swz)] = hb;
        hbuf[col * 256 + (u ^ swz)]       = hb;
        __syncthreads();
    }
}

extern "C" void kernel_launch(void* const* d_in, const int* in_sizes, int n_in,
                              void* d_out, int out_size, void* d_ws, size_t ws_size,
                              hipStream_t stream) {
    (void)in_sizes; (void)n_in; (void)out_size;
    if (ws_size < WSNEED) return;  // fail loudly (output stays poisoned)

    const float* noise = (const float*)d_in[0];
    const float* gap   = (const float*)d_in[1];
    const float* W_ih  = (const float*)d_in[2];
    const float* W_hh  = (const float*)d_in[3];
    const float* b_ih  = (const float*)d_in[4];
    const float* b_hh  = (const float*)d_in[5];
    const float* W1    = (const float*)d_in[6];
    const float* b1    = (const float*)d_in[7];
    const float* W2    = (const float*)d_in[8];
    const float* b2    = (const float*)d_in[9];
    char*  ws  = (char*)d_ws;
    float* out = (float*)d_out;

    hipLaunchKernelGGL(prep_gates, dim3(NGT * NKC), dim3(64), 0, stream, W_ih, W_hh, ws);
    hipLaunchKernelGGL(prep_w1,    dim3(16 * 8),    dim3(64), 0, stream, W1, ws);
    hipLaunchKernelGGL(prep_small, dim3(1), dim3(1024), 0, stream, b_ih, b_hh, ws);
    hipLaunchKernelGGL(lstm_main,  dim3(GROUPS * SLICES), dim3(512), 0, stream,
                       noise, gap, b1, W2, b2, ws, out);
}

// Round 4
// 3131.610 us; speedup vs baseline: 6.5541x; 1.6625x over previous
//
#include <hip/hip_runtime.h>
#include <stdint.h>
#include <stddef.h>

typedef __bf16 bf16x8 __attribute__((ext_vector_type(8)));
typedef float f32x4 __attribute__((ext_vector_type(4)));

#define MFMA16(a, b, c) __builtin_amdgcn_mfma_f32_16x16x32_bf16((a), (b), (c), 0, 0, 0)

// problem dims
#define TSTEPS 1024
#define NDIM   64
#define NKC    10     // K = 320: 0..63 noise | 64..319 h  (x-cols handled in VALU)
#define NGT    64     // 1024/16 gate row tiles
#define MB     16     // batch rows per group
#define GROUPS 32
#define SLICES 8      // blocks per group; each owns 32 hidden units

// workspace layout (bytes)
#define GOFF    ((size_t)0)
#define GBYTES  ((size_t)NGT * NKC * 1024)       // 655360
#define W1OFF   (GOFF + GBYTES)
#define W1BYTES ((size_t)16 * 8 * 1024)          // 131072
#define BOFF    (W1OFF + W1BYTES)                // 1024 f32 reordered gate bias
#define XOFF    (BOFF + 4096)                    // mailbox: 256 slices * 2 parity * 512 u32
#define XBYTES  ((size_t)256 * 2 * 512 * 4)      // 1 MiB
#define WSNEED  (XOFF + XBYTES)

__device__ __forceinline__ uint16_t f2bf(float f) {
    union { float f; uint32_t u; } v; v.f = f;
    return (uint16_t)((v.u + 0x7FFFu + ((v.u >> 16) & 1u)) >> 16);  // RNE
}
__device__ __forceinline__ float fsig(float x) { return 1.0f / (1.0f + __expf(-x)); }
__device__ __forceinline__ float ftanh(float x) { return 2.0f / (1.0f + __expf(-2.0f * x)) - 1.0f; }

// lgkmcnt-only barrier: does NOT drain vmcnt, so prefetches/mailbox stores stay in flight
__device__ __forceinline__ void bar_lgkm() {
    asm volatile("s_waitcnt lgkmcnt(0)" ::: "memory");
    __builtin_amdgcn_s_barrier();
    asm volatile("" ::: "memory");
}

// ---- prep: gate weights [1024 x 320] bf16, rows interleaved rho = 4*unit + gate,
//      frag-major: frag F=(T*NKC+kc), lane l holds A[16T+(l&15)][32kc+8*(l>>4)+j]
//      k map: 0..63 -> noise (W_ih cols 3..66); 64..319 -> h (W_hh)
__global__ void prep_gates(const float* __restrict__ W_ih, const float* __restrict__ W_hh,
                           char* __restrict__ ws) {
    int F = blockIdx.x;
    int T = F / NKC, kc = F - T * NKC;
    int l = threadIdx.x;
    int row  = 16 * T + (l & 15);
    int unit = row >> 2, gt = row & 3;
    int orig = gt * 256 + unit;              // torch gate order i,f,g,o blocks of 256
    uint32_t w[4];
#pragma unroll
    for (int p = 0; p < 4; ++p) {
        float v[2];
#pragma unroll
        for (int e = 0; e < 2; ++e) {
            int k = 32 * kc + 8 * (l >> 4) + 2 * p + e;
            v[e] = (k < 64) ? W_ih[orig * 67 + 3 + k] : W_hh[orig * 256 + (k - 64)];
        }
        w[p] = (uint32_t)f2bf(v[0]) | ((uint32_t)f2bf(v[1]) << 16);
    }
    *(uint4*)(ws + GOFF + (size_t)F * 1024 + (size_t)l * 16) = make_uint4(w[0], w[1], w[2], w[3]);
}

// ---- prep: W1 [256 x 256] bf16, frag-major
__global__ void prep_w1(const float* __restrict__ W1, char* __restrict__ ws) {
    int F = blockIdx.x;
    int T = F / 8, kc = F - T * 8;
    int l = threadIdx.x;
    int row = 16 * T + (l & 15);
    uint32_t w[4];
#pragma unroll
    for (int p = 0; p < 4; ++p) {
        int k = 32 * kc + 8 * (l >> 4) + 2 * p;
        w[p] = (uint32_t)f2bf(W1[row * 256 + k]) | ((uint32_t)f2bf(W1[row * 256 + k + 1]) << 16);
    }
    *(uint4*)(ws + W1OFF + (size_t)F * 1024 + (size_t)l * 16) = make_uint4(w[0], w[1], w[2], w[3]);
}

// ---- prep: reordered gate bias
__global__ void prep_small(const float* __restrict__ b_ih, const float* __restrict__ b_hh,
                           char* __restrict__ ws) {
    int t = threadIdx.x;
    float* sb = (float*)(ws + BOFF);
    if (t < 1024) {
        int unit = t >> 2, gt = t & 3;
        int orig = gt * 256 + unit;
        sb[t] = b_ih[orig] + b_hh[orig];
    }
}

// ---- main: 256 blocks (32 groups x 8 slices), 512 threads, weights in VGPRs,
//      tag-in-payload mailbox exchange (1 u32 per thread per step)
__global__ __launch_bounds__(512, 2) void lstm_main(
        const float* __restrict__ noise, const float* __restrict__ gap,
        const float* __restrict__ W_ih, const float* __restrict__ b1p,
        const float* __restrict__ W2p, const float* __restrict__ b2p,
        char* __restrict__ ws, float* __restrict__ out) {
    __shared__ uint16_t act[MB * 320];   // [batch][k], XOR-swizzled, bf16; h at 64..319
    __shared__ float dp_part[16][9];     // padded: conflict-free
    __shared__ float gxy[16][2];

    const int tid  = threadIdx.x;
    const int w    = tid >> 6;
    const int lane = tid & 63;
    const int q    = lane >> 4;
    const int col  = lane & 15;
    const int g    = blockIdx.x >> 3;
    const int s    = blockIdx.x & 7;
    const int b0   = g * MB;
    const int swz  = (col & 7) << 3;

    const uint4* gfr  = (const uint4*)(ws + GOFF);
    const uint4* w1fr = (const uint4*)(ws + W1OFF);
    const float* bias = (const float*)(ws + BOFF);
    uint32_t* pay = (uint32_t*)(ws + XOFF);

    for (int i = tid; i < MB * 320; i += 512) act[i] = 0;

    // ---- weights -> VGPRs
    const int T = 8 * s + w;             // this wave's gate row-tile (global)
    uint4 gw[NKC];
#pragma unroll
    for (int kc = 0; kc < NKC; ++kc) gw[kc] = gfr[(size_t)(T * NKC + kc) * 64 + lane];
    uint4 w1w[16];                        // full W1: wave w holds head row-tiles 2w, 2w+1
#pragma unroll
    for (int i = 0; i < 2; ++i)
#pragma unroll
        for (int kc = 0; kc < 8; ++kc)
            w1w[i * 8 + kc] = w1fr[(size_t)((2 * w + i) * 8 + kc) * 64 + lane];

    const int rb = 16 * T + 4 * q;
    const float bI = bias[rb], bF = bias[rb + 1], bG = bias[rb + 2], bO = bias[rb + 3];
    float wx0[4], wx1[4], wx2[4];        // f32 x-column weights (rank-3 VALU path)
#pragma unroll
    for (int r = 0; r < 4; ++r) {
        int row = rb + r;
        int orig = (row & 3) * 256 + (row >> 2);
        wx0[r] = W_ih[orig * 67 + 0];
        wx1[r] = W_ih[orig * 67 + 1];
        wx2[r] = W_ih[orig * 67 + 2] * 24.0f;
    }
    float b1r[8], w2r[8];
#pragma unroll
    for (int a = 0; a < 2; ++a)
#pragma unroll
        for (int r = 0; r < 4; ++r) {
            int row = 32 * w + 16 * a + 4 * q + r;
            b1r[4 * a + r] = b1p[row];
            w2r[4 * a + r] = W2p[row];
        }
    const float b2v = b2p[0];

    // ---- prefetch t=0
    const int nbr = tid >> 5, nj = (tid & 31) * 2;
    const float* nptr = noise + (size_t)(b0 + nbr) * TSTEPS * NDIM + nj;
    float2 npf = *(const float2*)nptr;
    const bool xlead = (w == 7 && lane < 16);
    float2 gpf = make_float2(0.f, 0.f);
    if (xlead) gpf = *(const float2*)(gap + (size_t)(b0 + col) * (TSTEPS + 1) * 2);

    float creg = 0.f;
    const f32x4 fz = {0.f, 0.f, 0.f, 0.f};
    const int myidx = g * 8 + s;
    const int myunit = 32 * s + 4 * w + q;

    __syncthreads();

#pragma unroll 1
    for (int t = 0; t <= TSTEPS; ++t) {
        // ---- Phase A: noise staging, gap/gxy staging, mailbox poll+scatter
        if (t < TSTEPS) {
            uint32_t nv = (uint32_t)f2bf(npf.x) | ((uint32_t)f2bf(npf.y) << 16);
            int sw = (nbr & 7) << 3;
            *(uint32_t*)&act[nbr * 320 + (nj ^ sw)] = nv;
            if (t + 1 < TSTEPS) npf = *(const float2*)(nptr + (size_t)(t + 1) * NDIM);
        }
        if (xlead) {
            gxy[col][0] = gpf.x; gxy[col][1] = gpf.y;
            if (s == 0) {
                float* o = out + ((size_t)(b0 + col) * (TSTEPS + 1) + t) * 3;
                o[0] = gpf.x; o[1] = gpf.y;
            }
            if (t < TSTEPS)
                gpf = *(const float2*)(gap + ((size_t)(b0 + col) * (TSTEPS + 1) + (t + 1)) * 2);
        }
        if (t > 0) {   // receive 7 peer h-slices: tag match == data valid
            const unsigned tag = (unsigned)t;
            const int par = t & 1;
            unsigned pend = 0x7f;
            uint32_t vv[7];
            do {
#pragma unroll
                for (int pi = 0; pi < 7; ++pi)
                    if (pend & (1u << pi)) {
                        int p = (s + 1 + pi) & 7;
                        vv[pi] = __hip_atomic_load(
                            &pay[(((g * 8 + p) * 2 + par) << 9) + 64 * w + lane],
                            __ATOMIC_RELAXED, __HIP_MEMORY_SCOPE_AGENT);
                    }
#pragma unroll
                for (int pi = 0; pi < 7; ++pi)
                    if ((pend & (1u << pi)) && (vv[pi] >> 16) == tag) {
                        int p = (s + 1 + pi) & 7;
                        int u = 32 * p + 4 * w + q;
                        act[col * 320 + ((64 + u) ^ swz)] = (uint16_t)vv[pi];
                        pend &= ~(1u << pi);
                    }
            } while (pend);
        }
        bar_lgkm();

        // ---- Phase B: full head (redundant per block), dp partials
        f32x4 h0 = fz, h1 = fz;
#pragma unroll
        for (int kc = 0; kc < 8; ++kc) {
            bf16x8 bv = *(const bf16x8*)&act[col * 320 + ((64 + 32 * kc + 8 * q) ^ swz)];
            h0 = MFMA16(__builtin_bit_cast(bf16x8, w1w[kc]),     bv, h0);
            h1 = MFMA16(__builtin_bit_cast(bf16x8, w1w[8 + kc]), bv, h1);
        }
        float part = 0.f;
#pragma unroll
        for (int r = 0; r < 4; ++r) {
            part += ftanh(h0[r] + b1r[r])     * w2r[r];
            part += ftanh(h1[r] + b1r[4 + r]) * w2r[4 + r];
        }
        part += __shfl_xor(part, 16);
        part += __shfl_xor(part, 32);
        if (q == 0) dp_part[col][w] = part;
        bar_lgkm();

        // dp finalize: every lane, redundantly (LDS broadcast reads)
        const float* dpp = &dp_part[col][0];
        float inner = b2v + ((dpp[0] + dpp[1]) + (dpp[2] + dpp[3]))
                          + ((dpp[4] + dpp[5]) + (dpp[6] + dpp[7]));
        float tdp = ftanh(inner);

        if (t == TSTEPS) {
            if (s == 0 && w == 0 && q == 0)
                out[((size_t)(b0 + col) * (TSTEPS + 1) + t) * 3 + 2] = 24.0f * tdp;
            break;
        }

        // ---- Phase C: gate MFMA (noise+h) + rank-3 x update + LSTM elementwise
        f32x4 ga = fz;
#pragma unroll
        for (int kc = 0; kc < NKC; ++kc) {
            bf16x8 bv = *(const bf16x8*)&act[col * 320 + ((32 * kc + 8 * q) ^ swz)];
            ga = MFMA16(__builtin_bit_cast(bf16x8, gw[kc]), bv, ga);
        }
        const float g0 = gxy[col][0], g1 = gxy[col][1];
        float ii = ga[0] + bI + wx0[0] * g0 + wx1[0] * g1 + wx2[0] * tdp;
        float ff = ga[1] + bF + wx0[1] * g0 + wx1[1] * g1 + wx2[1] * tdp;
        float gg = ga[2] + bG + wx0[2] * g0 + wx1[2] * g1 + wx2[2] * tdp;
        float oo = ga[3] + bO + wx0[3] * g0 + wx1[3] * g1 + wx2[3] * tdp;
        float cn = fsig(ff) * creg + fsig(ii) * ftanh(gg);
        creg = cn;
        float hv = fsig(oo) * ftanh(cn);
        uint16_t hb = f2bf(hv);
        // publish: fire-and-forget tagged word (tag = t+1)
        __hip_atomic_store(&pay[((myidx * 2 + ((t + 1) & 1)) << 9) + 64 * w + lane],
                           ((uint32_t)(t + 1) << 16) | (uint32_t)hb,
                           __ATOMIC_RELAXED, __HIP_MEMORY_SCOPE_AGENT);
        act[col * 320 + ((64 + myunit) ^ swz)] = hb;
        if (s == 0 && w == 0 && q == 0)
            out[((size_t)(b0 + col) * (TSTEPS + 1) + t) * 3 + 2] = 24.0f * tdp;
        bar_lgkm();
    }
}

extern "C" void kernel_launch(void* const* d_in, const int* in_sizes, int n_in,
                              void* d_out, int out_size, void* d_ws, size_t ws_size,
                              hipStream_t stream) {
    (void)in_sizes; (void)n_in; (void)out_size;
    if (ws_size < WSNEED) return;  // fail loudly (output stays poisoned)

    const float* noise = (const float*)d_in[0];
    const float* gap   = (const float*)d_in[1];
    const float* W_ih  = (const float*)d_in[2];
    const float* W_hh  = (const float*)d_in[3];
    const float* b_ih  = (const float*)d_in[4];
    const float* b_hh  = (const float*)d_in[5];
    const float* W1    = (const float*)d_in[6];
    const float* b1    = (const float*)d_in[7];
    const float* W2    = (const float*)d_in[8];
    const float* b2    = (const float*)d_in[9];
    char*  ws  = (char*)d_ws;
    float* out = (float*)d_out;

    hipMemsetAsync(ws + XOFF, 0, XBYTES, stream);   // mailbox tags -> 0 (replay-safe)
    hipLaunchKernelGGL(prep_gates, dim3(NGT * NKC), dim3(64), 0, stream, W_ih, W_hh, ws);
    hipLaunchKernelGGL(prep_w1,    dim3(16 * 8),    dim3(64), 0, stream, W1, ws);
    hipLaunchKernelGGL(prep_small, dim3(1), dim3(1024), 0, stream, b_ih, b_hh, ws);
    hipLaunchKernelGGL(lstm_main,  dim3(GROUPS * SLICES), dim3(512), 0, stream,
                       noise, gap, W_ih, b1, W2, b2, ws, out);
}